// Round 1
// baseline (444.620 us; speedup 1.0000x reference)
//
#include <hip/hip_runtime.h>

#define EPS 1e-5f

// ---------------------------------------------------------------------------
// Kernel 1: 1x1 conv (64->64) + BN + ReLU.
// Thread computes 8 output channels for one pixel; weight reads are
// wave-uniform -> scalar loads. X reads coalesced over x.
// ---------------------------------------------------------------------------
__global__ __launch_bounds__(256) void compress_kernel(
    const float* __restrict__ X, const float* __restrict__ W,
    const float* __restrict__ gamma, const float* __restrict__ beta,
    const float* __restrict__ mean, const float* __restrict__ var,
    float* __restrict__ out) {
  int id = blockIdx.x * 256 + threadIdx.x;   // 4 b * 8 cog * 128 y * 128 x
  int x = id & 127;
  int y = (id >> 7) & 127;
  int cog = (id >> 14) & 7;
  int b = id >> 17;
  const float* xb = X + b * 64 * 16384 + y * 128 + x;
  float acc[8];
#pragma unroll
  for (int u = 0; u < 8; ++u) acc[u] = 0.f;
#pragma unroll 8
  for (int ci = 0; ci < 64; ++ci) {
    float xv = xb[ci * 16384];
#pragma unroll
    for (int u = 0; u < 8; ++u)
      acc[u] = fmaf(W[(cog * 8 + u) * 64 + ci], xv, acc[u]);
  }
#pragma unroll
  for (int u = 0; u < 8; ++u) {
    int co = cog * 8 + u;
    float inv = gamma[co] * rsqrtf(var[co] + EPS);
    float v = fmaf(acc[u], inv, beta[co] - mean[co] * inv);
    out[((b * 64 + co) * 128 + y) * 128 + x] = fmaxf(v, 0.f);
  }
}

// ---------------------------------------------------------------------------
// Kernel 2: 3x3 conv (64->100) + bias + BN.
// Block = 16x16 pixel tile, grid.z = (b, ec) with ec selecting 25 of the 100
// output channels. Input staged in LDS in 16-channel chunks; weights read
// with wave-uniform addresses (compiler -> s_load, constant cache).
// ---------------------------------------------------------------------------
__global__ __launch_bounds__(256) void encode_kernel(
    const float* __restrict__ Wm1, const float* __restrict__ EW,
    const float* __restrict__ EB,
    const float* __restrict__ gamma, const float* __restrict__ beta,
    const float* __restrict__ mean, const float* __restrict__ var,
    float* __restrict__ enc) {
  const int tid = threadIdx.x;
  const int b = blockIdx.z >> 2, ec = blockIdx.z & 3;
  const int ty = tid >> 4, tx = tid & 15;
  const int y0 = blockIdx.y * 16, x0 = blockIdx.x * 16;
  __shared__ float in_t[16 * 324];   // 16 ci x 18 x 18
  float acc[25];
#pragma unroll
  for (int e = 0; e < 25; ++e) acc[e] = 0.f;

  for (int cc = 0; cc < 4; ++cc) {
    for (int idx = tid; idx < 5184; idx += 256) {
      int ci = idx / 324;
      int rem = idx - ci * 324;
      int iy = rem / 18;
      int ix = rem - iy * 18;
      int gy = y0 + iy - 1, gx = x0 + ix - 1;
      float v = 0.f;
      if ((unsigned)gy < 128u && (unsigned)gx < 128u)
        v = Wm1[((b * 64 + cc * 16 + ci) * 128 + gy) * 128 + gx];
      in_t[idx] = v;
    }
    __syncthreads();
    for (int ci = 0; ci < 16; ++ci) {
      float v[9];
      const float* it = in_t + ci * 324 + ty * 18 + tx;
#pragma unroll
      for (int t = 0; t < 9; ++t) v[t] = it[(t / 3) * 18 + (t % 3)];
      const float* wq = EW + (ec * 25 * 64 + cc * 16 + ci) * 9;  // + e*576
#pragma unroll
      for (int e = 0; e < 25; ++e) {
        const float* w = wq + e * 576;
#pragma unroll
        for (int t = 0; t < 9; ++t) acc[e] = fmaf(w[t], v[t], acc[e]);
      }
    }
    __syncthreads();
  }

  int gy = y0 + ty, gx = x0 + tx;
#pragma unroll
  for (int e = 0; e < 25; ++e) {
    int eg = ec * 25 + e;
    float inv = gamma[eg] * rsqrtf(var[eg] + EPS);
    float v = fmaf(acc[e] + EB[eg], inv, beta[eg] - mean[eg] * inv);
    enc[((b * 100 + eg) * 128 + gy) * 128 + gx] = v;
  }
}

// ---------------------------------------------------------------------------
// Kernel 3: fused pixel-shuffle + softmax(25) + CARAFE apply.
// Block = 8x8 low-res tile, one batch. The 4 subpixels of a low-res pixel
// share the same 25 X taps (only weights differ), so each thread holds the
// 50 weights (r1 fixed, both r2) in registers and streams 32 channels,
// writing float2 (both r2) per channel.
// LDS: wsm[64][101] logits->weights (stride 101: conflict-free);
//      xt[64][144] X tile (12x12, phase-3 lane pattern is exactly 2-way).
// ---------------------------------------------------------------------------
__global__ __launch_bounds__(256) void carafe_kernel(
    const float* __restrict__ X, const float* __restrict__ enc,
    float* __restrict__ out) {
  const int tid = threadIdx.x;
  const int b = blockIdx.z;
  const int y0 = blockIdx.y * 8, x0 = blockIdx.x * 8;
  __shared__ float wsm[64 * 101];
  __shared__ float xt[64 * 144];

  // load logits, de-pixel-shuffled: channel e = k*4 + r1*2 + r2
  for (int idx = tid; idx < 6400; idx += 256) {
    int e = idx >> 6, p = idx & 63;
    int py = p >> 3, px = p & 7;
    float v = enc[((b * 100 + e) * 128 + y0 + py) * 128 + x0 + px];
    wsm[p * 101 + (e & 3) * 25 + (e >> 2)] = v;
  }
  // load X tile (64c x 12x12, halo 2, zero-padded)
  for (int idx = tid; idx < 9216; idx += 256) {
    int c = idx / 144;
    int rem = idx - c * 144;
    int iy = rem / 12, ix = rem - iy * 12;
    int gy = y0 + iy - 2, gx = x0 + ix - 2;
    float v = 0.f;
    if ((unsigned)gy < 128u && (unsigned)gx < 128u)
      v = X[((b * 64 + c) * 128 + gy) * 128 + gx];
    xt[idx] = v;
  }
  __syncthreads();

  // softmax over k=25 per (pixel, subpixel)
  {
    int p = tid & 63, r = tid >> 6;
    float* wp = wsm + p * 101 + r * 25;
    float m = wp[0];
#pragma unroll
    for (int k = 1; k < 25; ++k) m = fmaxf(m, wp[k]);
    float s = 0.f;
#pragma unroll
    for (int k = 0; k < 25; ++k) {
      float e = __expf(wp[k] - m);
      wp[k] = e;
      s += e;
    }
    float inv = 1.f / s;
#pragma unroll
    for (int k = 0; k < 25; ++k) wp[k] *= inv;
  }
  __syncthreads();

  // apply
  {
    int p = tid & 63, q = tid >> 6;
    int r1 = q & 1, cq = q >> 1;
    int py = p >> 3, px = p & 7;
    float wf0[25], wf1[25];
    const float* wp = wsm + p * 101 + r1 * 50;
#pragma unroll
    for (int k = 0; k < 25; ++k) {
      wf0[k] = wp[k];
      wf1[k] = wp[k + 25];
    }
    int yq = (y0 + py) * 2 + r1;
    int xq = (x0 + px) * 2;
    const float* xb = xt + py * 12 + px;
#pragma unroll 2
    for (int ci = 0; ci < 32; ++ci) {
      int c = cq * 32 + ci;
      const float* xc = xb + c * 144;
      float a0 = 0.f, a1 = 0.f;
#pragma unroll
      for (int k = 0; k < 25; ++k) {
        float xv = xc[(k / 5) * 12 + (k % 5)];
        a0 = fmaf(wf0[k], xv, a0);
        a1 = fmaf(wf1[k], xv, a1);
      }
      float2* o = reinterpret_cast<float2*>(
          out + ((size_t)(b * 64 + c) * 256 + yq) * 256 + xq);
      *o = make_float2(a0, a1);
    }
  }
}

// ---------------------------------------------------------------------------
extern "C" void kernel_launch(void* const* d_in, const int* in_sizes, int n_in,
                              void* d_out, int out_size, void* d_ws, size_t ws_size,
                              hipStream_t stream) {
  const float* X          = (const float*)d_in[0];
  const float* comp_w     = (const float*)d_in[1];
  const float* comp_gamma = (const float*)d_in[2];
  const float* comp_beta  = (const float*)d_in[3];
  const float* comp_mean  = (const float*)d_in[4];
  const float* comp_var   = (const float*)d_in[5];
  const float* enc_w      = (const float*)d_in[6];
  const float* enc_b      = (const float*)d_in[7];
  const float* enc_gamma  = (const float*)d_in[8];
  const float* enc_beta   = (const float*)d_in[9];
  const float* enc_mean   = (const float*)d_in[10];
  const float* enc_var    = (const float*)d_in[11];
  float* out = (float*)d_out;

  float* Wm1 = (float*)d_ws;                         // 4*64*128*128 = 16.78 MB
  float* enc = Wm1 + (size_t)4 * 64 * 128 * 128;     // 4*100*128*128 = 26.21 MB

  compress_kernel<<<2048, 256, 0, stream>>>(X, comp_w, comp_gamma, comp_beta,
                                            comp_mean, comp_var, Wm1);
  encode_kernel<<<dim3(8, 8, 16), 256, 0, stream>>>(Wm1, enc_w, enc_b, enc_gamma,
                                                    enc_beta, enc_mean, enc_var, enc);
  carafe_kernel<<<dim3(16, 16, 4), 256, 0, stream>>>(X, enc, out);
}

// Round 2
// 210.439 us; speedup vs baseline: 2.1128x; 2.1128x over previous
//
#include <hip/hip_runtime.h>

#define EPS 1e-5f

typedef __attribute__((ext_vector_type(8))) short short8;
typedef __attribute__((ext_vector_type(4))) float float4v;

__device__ inline unsigned short f2bf(float f) {
  unsigned u = __float_as_uint(f);
  unsigned r = (u + 0x7fffu + ((u >> 16) & 1u)) >> 16;
  return (unsigned short)r;
}

// ---------------------------------------------------------------------------
// xform: fold BN scale into weights.
//  - Awt bf16 [kc(18)][mt(8)][q(4)][ml(16)][j(8)]  (A-fragment-ready, e padded
//    to 128 with zeros). k-chunk kc = tap*2 + half; k-in-chunk = ci_local,
//    ci = half*32 + q*8 + j.
//  - Wc fp32 [ci(64)][co(64)] transposed compress weights * inv[co].
// ---------------------------------------------------------------------------
__global__ __launch_bounds__(256) void xform_kernel(
    const float* __restrict__ enc_w, const float* __restrict__ enc_gamma,
    const float* __restrict__ enc_var, const float* __restrict__ comp_w,
    const float* __restrict__ comp_gamma, const float* __restrict__ comp_var,
    ushort* __restrict__ Awt, float* __restrict__ Wc) {
  int u = blockIdx.x * 256 + threadIdx.x;
  if (u < 9216) {
    int kc = u >> 9, rem = u & 511;
    int mt = rem >> 6, q = (rem >> 4) & 3, ml = rem & 15;
    int e = mt * 16 + ml;
    int t = kc >> 1, h = kc & 1;
    int dy = t / 3, dx = t - dy * 3;
    float inv = (e < 100) ? enc_gamma[e] * rsqrtf(enc_var[e] + EPS) : 0.f;
    ushort o[8];
#pragma unroll
    for (int j = 0; j < 8; ++j) {
      int ci = h * 32 + q * 8 + j;
      float w = (e < 100) ? enc_w[(e * 64 + ci) * 9 + dy * 3 + dx] * inv : 0.f;
      o[j] = f2bf(w);
    }
    uint4 v;
    v.x = (uint)o[0] | ((uint)o[1] << 16);
    v.y = (uint)o[2] | ((uint)o[3] << 16);
    v.z = (uint)o[4] | ((uint)o[5] << 16);
    v.w = (uint)o[6] | ((uint)o[7] << 16);
    *reinterpret_cast<uint4*>(Awt + (size_t)u * 8) = v;
  } else if (u < 9216 + 4096) {
    int v = u - 9216;
    int co = v & 63;
    float inv = comp_gamma[co] * rsqrtf(comp_var[co] + EPS);
    Wc[v] = comp_w[co * 64 + (v >> 6)] * inv;
  }
}

__global__ void bias_kernel(
    const float* __restrict__ enc_b, const float* __restrict__ enc_gamma,
    const float* __restrict__ enc_beta, const float* __restrict__ enc_mean,
    const float* __restrict__ enc_var, const float* __restrict__ comp_gamma,
    const float* __restrict__ comp_beta, const float* __restrict__ comp_mean,
    const float* __restrict__ comp_var, float* __restrict__ bias2,
    float* __restrict__ bias_c) {
  int t = threadIdx.x;
  if (t < 128) {
    float v = 0.f;
    if (t < 100) {
      float inv = enc_gamma[t] * rsqrtf(enc_var[t] + EPS);
      v = enc_b[t] * inv + enc_beta[t] - enc_mean[t] * inv;
    }
    bias2[t] = v;
  } else if (t < 192) {
    int c = t - 128;
    float inv = comp_gamma[c] * rsqrtf(comp_var[c] + EPS);
    bias_c[c] = comp_beta[c] - comp_mean[c] * inv;
  }
}

// ---------------------------------------------------------------------------
// compress: 1x1 conv 64->64 + BN + ReLU, thread-per-pixel, 64 fp32 acc.
// Output bf16 pixel-major [b][y][x][ci] (128 B contiguous per pixel) so the
// encode kernel can vector-load im2col fragments.
// ---------------------------------------------------------------------------
__global__ __launch_bounds__(256) void compress_kernel(
    const float* __restrict__ X, const float* __restrict__ Wc,
    const float* __restrict__ bias_c, ushort* __restrict__ out) {
  int p = blockIdx.x * 256 + threadIdx.x;   // 65536 pixels (b,y,x)
  int b = p >> 14, rem = p & 16383;
  const float* xb = X + ((size_t)b << 20) + rem;
  float acc[64];
#pragma unroll
  for (int co = 0; co < 64; ++co) acc[co] = 0.f;
#pragma unroll 4
  for (int ci = 0; ci < 64; ++ci) {
    float xv = xb[(size_t)ci << 14];
    const float* wr = Wc + (ci << 6);
#pragma unroll
    for (int co = 0; co < 64; ++co) acc[co] = fmaf(wr[co], xv, acc[co]);
  }
  alignas(16) ushort o[64];
#pragma unroll
  for (int co = 0; co < 64; ++co)
    o[co] = f2bf(fmaxf(acc[co] + bias_c[co], 0.f));
  uint4* dst = reinterpret_cast<uint4*>(out + (size_t)p * 64);
  const uint4* src = reinterpret_cast<const uint4*>(o);
#pragma unroll
  for (int u = 0; u < 8; ++u) dst[u] = src[u];
}

// ---------------------------------------------------------------------------
// encode: 3x3 conv (64->100) as implicit GEMM on MFMA bf16 16x16x32.
// Block = 16x16 pixel tile of one image; M=128 (e padded), K=576 (18 chunks).
// Wave w: mt half = w&1 (4 m-tiles), nt half = w>>1 (8 rows). 32 MFMA/chunk.
// Xt LDS: [pos(18x18)][ci] with ci padded 64->72 -> ds_read_b128 B-frags at
// the 8-phase floor (classes (px+q)%8). A-frags: 1KB coalesced global loads
// from the pre-swizzled Awt (L2-resident).
// ---------------------------------------------------------------------------
__global__ __launch_bounds__(256) void encode_mfma(
    const ushort* __restrict__ Wm1t, const ushort* __restrict__ Awt,
    const float* __restrict__ bias2, float* __restrict__ enc) {
  __shared__ __align__(16) ushort Xt[324 * 72];
  __shared__ float bsm[128];
  const int tid = threadIdx.x;
  const int b = blockIdx.z;
  const int y0 = blockIdx.y * 16, x0 = blockIdx.x * 16;

  if (tid < 128) bsm[tid] = bias2[tid];
  for (int u = tid; u < 2592; u += 256) {   // 324 pos x 8 ci-groups
    int pos = u >> 3, cg = u & 7;
    int iy = pos / 18, ix = pos - iy * 18;
    int gy = y0 + iy - 1, gx = x0 + ix - 1;
    uint4 v = make_uint4(0, 0, 0, 0);
    if ((unsigned)gy < 128u && (unsigned)gx < 128u)
      v = *reinterpret_cast<const uint4*>(
          Wm1t + ((((size_t)b << 14) + (gy << 7) + gx) << 6) + cg * 8);
    *reinterpret_cast<uint4*>(&Xt[pos * 72 + cg * 8]) = v;
  }
  __syncthreads();

  const int wave = tid >> 6, lane = tid & 63;
  const int q = lane >> 4, px = lane & 15;
  const int mtg = wave & 1, ntg = wave >> 1;

  float4v acc[4][8];
#pragma unroll
  for (int a = 0; a < 4; ++a)
#pragma unroll
    for (int i = 0; i < 8; ++i) acc[a][i] = (float4v){0.f, 0.f, 0.f, 0.f};

  const short8* Ap = reinterpret_cast<const short8*>(Awt);
#pragma unroll
  for (int kc = 0; kc < 18; ++kc) {
    const int t = kc >> 1, h = kc & 1;
    const int dy = t / 3, dx = t - dy * 3;
    short8 af[4];
#pragma unroll
    for (int a = 0; a < 4; ++a)
      af[a] = Ap[kc * 512 + (mtg * 4 + a) * 64 + lane];
    short8 bfr[8];
#pragma unroll
    for (int i = 0; i < 8; ++i) {
      int nt = ntg * 8 + i;
      bfr[i] = *reinterpret_cast<const short8*>(
          &Xt[((nt + dy) * 18 + (px + dx)) * 72 + h * 32 + q * 8]);
    }
#pragma unroll
    for (int a = 0; a < 4; ++a)
#pragma unroll
      for (int i = 0; i < 8; ++i)
        acc[a][i] = __builtin_amdgcn_mfma_f32_16x16x32_bf16(
            af[a], bfr[i], acc[a][i], 0, 0, 0);
  }

#pragma unroll
  for (int a = 0; a < 4; ++a) {
    int mt = mtg * 4 + a;
#pragma unroll
    for (int i = 0; i < 8; ++i) {
      int nt = ntg * 8 + i;
#pragma unroll
      for (int r = 0; r < 4; ++r) {
        int e = mt * 16 + q * 4 + r;
        if (e < 100)
          enc[(((size_t)b * 100 + e) * 128 + y0 + nt) * 128 + x0 + px] =
              acc[a][i][r] + bsm[e];
      }
    }
  }
}

// ---------------------------------------------------------------------------
// carafe: fused pixel-shuffle + softmax(25) + apply (unchanged from R1).
// ---------------------------------------------------------------------------
__global__ __launch_bounds__(256) void carafe_kernel(
    const float* __restrict__ X, const float* __restrict__ enc,
    float* __restrict__ out) {
  const int tid = threadIdx.x;
  const int b = blockIdx.z;
  const int y0 = blockIdx.y * 8, x0 = blockIdx.x * 8;
  __shared__ float wsm[64 * 101];
  __shared__ float xt[64 * 144];

  for (int idx = tid; idx < 6400; idx += 256) {
    int e = idx >> 6, p = idx & 63;
    int py = p >> 3, px = p & 7;
    float v = enc[((b * 100 + e) * 128 + y0 + py) * 128 + x0 + px];
    wsm[p * 101 + (e & 3) * 25 + (e >> 2)] = v;
  }
  for (int idx = tid; idx < 9216; idx += 256) {
    int c = idx / 144;
    int rem = idx - c * 144;
    int iy = rem / 12, ix = rem - iy * 12;
    int gy = y0 + iy - 2, gx = x0 + ix - 2;
    float v = 0.f;
    if ((unsigned)gy < 128u && (unsigned)gx < 128u)
      v = X[((b * 64 + c) * 128 + gy) * 128 + gx];
    xt[idx] = v;
  }
  __syncthreads();

  {
    int p = tid & 63, r = tid >> 6;
    float* wp = wsm + p * 101 + r * 25;
    float m = wp[0];
#pragma unroll
    for (int k = 1; k < 25; ++k) m = fmaxf(m, wp[k]);
    float s = 0.f;
#pragma unroll
    for (int k = 0; k < 25; ++k) {
      float e = __expf(wp[k] - m);
      wp[k] = e;
      s += e;
    }
    float inv = 1.f / s;
#pragma unroll
    for (int k = 0; k < 25; ++k) wp[k] *= inv;
  }
  __syncthreads();

  {
    int p = tid & 63, qq = tid >> 6;
    int r1 = qq & 1, cq = qq >> 1;
    int py = p >> 3, px = p & 7;
    float wf0[25], wf1[25];
    const float* wp = wsm + p * 101 + r1 * 50;
#pragma unroll
    for (int k = 0; k < 25; ++k) {
      wf0[k] = wp[k];
      wf1[k] = wp[k + 25];
    }
    int yq = (y0 + py) * 2 + r1;
    int xq = (x0 + px) * 2;
    const float* xb = xt + py * 12 + px;
#pragma unroll 2
    for (int ci = 0; ci < 32; ++ci) {
      int c = cq * 32 + ci;
      const float* xc = xb + c * 144;
      float a0 = 0.f, a1 = 0.f;
#pragma unroll
      for (int k = 0; k < 25; ++k) {
        float xv = xc[(k / 5) * 12 + (k % 5)];
        a0 = fmaf(wf0[k], xv, a0);
        a1 = fmaf(wf1[k], xv, a1);
      }
      float2* o = reinterpret_cast<float2*>(
          out + ((size_t)(b * 64 + c) * 256 + yq) * 256 + xq);
      *o = make_float2(a0, a1);
    }
  }
}

// ---------------------------------------------------------------------------
extern "C" void kernel_launch(void* const* d_in, const int* in_sizes, int n_in,
                              void* d_out, int out_size, void* d_ws, size_t ws_size,
                              hipStream_t stream) {
  const float* X          = (const float*)d_in[0];
  const float* comp_w     = (const float*)d_in[1];
  const float* comp_gamma = (const float*)d_in[2];
  const float* comp_beta  = (const float*)d_in[3];
  const float* comp_mean  = (const float*)d_in[4];
  const float* comp_var   = (const float*)d_in[5];
  const float* enc_w      = (const float*)d_in[6];
  const float* enc_b      = (const float*)d_in[7];
  const float* enc_gamma  = (const float*)d_in[8];
  const float* enc_beta   = (const float*)d_in[9];
  const float* enc_mean   = (const float*)d_in[10];
  const float* enc_var    = (const float*)d_in[11];
  float* out = (float*)d_out;

  char* ws = (char*)d_ws;
  ushort* Wm1t  = (ushort*)(ws);                    // 8,388,608 B
  float*  enc   = (float*)(ws + 8388608);           // 26,214,400 B
  ushort* Awt   = (ushort*)(ws + 34603008);         // 147,456 B
  float*  Wc    = (float*)(ws + 34750464);          // 16,384 B
  float*  bias2 = (float*)(ws + 34766848);          // 512 B
  float*  biasc = (float*)(ws + 34767360);          // 256 B

  xform_kernel<<<52, 256, 0, stream>>>(enc_w, enc_gamma, enc_var,
                                       comp_w, comp_gamma, comp_var, Awt, Wc);
  bias_kernel<<<1, 256, 0, stream>>>(enc_b, enc_gamma, enc_beta, enc_mean,
                                     enc_var, comp_gamma, comp_beta, comp_mean,
                                     comp_var, bias2, biasc);
  compress_kernel<<<256, 256, 0, stream>>>(X, Wc, biasc, Wm1t);
  encode_mfma<<<dim3(8, 8, 4), 256, 0, stream>>>(Wm1t, Awt, bias2, enc);
  carafe_kernel<<<dim3(16, 16, 4), 256, 0, stream>>>(X, enc, out);
}

// Round 4
// 188.962 us; speedup vs baseline: 2.3530x; 1.1137x over previous
//
#include <hip/hip_runtime.h>

#define EPS 1e-5f

typedef __attribute__((ext_vector_type(8))) short short8;
typedef __attribute__((ext_vector_type(4))) float float4v;

__device__ inline unsigned short f2bf(float f) {
  unsigned u = __float_as_uint(f);
  unsigned r = (u + 0x7fffu + ((u >> 16) & 1u)) >> 16;
  return (unsigned short)r;
}

// ---------------------------------------------------------------------------
// xform: fold BN scale into weights.
//  - Awt bf16 [kc(18)][mt(8)][q(4)][ml(16)][j(8)] (A-fragment-ready, e pad 128)
//  - Wc fp32 [ci(64)][co(64)] transposed compress weights * inv[co].
// ---------------------------------------------------------------------------
__global__ __launch_bounds__(256) void xform_kernel(
    const float* __restrict__ enc_w, const float* __restrict__ enc_gamma,
    const float* __restrict__ enc_var, const float* __restrict__ comp_w,
    const float* __restrict__ comp_gamma, const float* __restrict__ comp_var,
    ushort* __restrict__ Awt, float* __restrict__ Wc) {
  int u = blockIdx.x * 256 + threadIdx.x;
  if (u < 9216) {
    int kc = u >> 9, rem = u & 511;
    int mt = rem >> 6, q = (rem >> 4) & 3, ml = rem & 15;
    int e = mt * 16 + ml;
    int t = kc >> 1, h = kc & 1;
    int dy = t / 3, dx = t - dy * 3;
    float inv = (e < 100) ? enc_gamma[e] * rsqrtf(enc_var[e] + EPS) : 0.f;
    ushort o[8];
#pragma unroll
    for (int j = 0; j < 8; ++j) {
      int ci = h * 32 + q * 8 + j;
      float w = (e < 100) ? enc_w[(e * 64 + ci) * 9 + dy * 3 + dx] * inv : 0.f;
      o[j] = f2bf(w);
    }
    uint4 v;
    v.x = (uint)o[0] | ((uint)o[1] << 16);
    v.y = (uint)o[2] | ((uint)o[3] << 16);
    v.z = (uint)o[4] | ((uint)o[5] << 16);
    v.w = (uint)o[6] | ((uint)o[7] << 16);
    *reinterpret_cast<uint4*>(Awt + (size_t)u * 8) = v;
  } else if (u < 9216 + 4096) {
    int v = u - 9216;
    int co = v & 63;
    float inv = comp_gamma[co] * rsqrtf(comp_var[co] + EPS);
    Wc[v] = comp_w[co * 64 + (v >> 6)] * inv;
  }
}

__global__ void bias_kernel(
    const float* __restrict__ enc_b, const float* __restrict__ enc_gamma,
    const float* __restrict__ enc_beta, const float* __restrict__ enc_mean,
    const float* __restrict__ enc_var, const float* __restrict__ comp_gamma,
    const float* __restrict__ comp_beta, const float* __restrict__ comp_mean,
    const float* __restrict__ comp_var, float* __restrict__ bias2,
    float* __restrict__ bias_c) {
  int t = threadIdx.x;
  if (t < 128) {
    float v = 0.f;
    if (t < 100) {
      float inv = enc_gamma[t] * rsqrtf(enc_var[t] + EPS);
      v = enc_b[t] * inv + enc_beta[t] - enc_mean[t] * inv;
    }
    bias2[t] = v;
  } else if (t < 192) {
    int c = t - 128;
    float inv = comp_gamma[c] * rsqrtf(comp_var[c] + EPS);
    bias_c[c] = comp_beta[c] - comp_mean[c] * inv;
  }
}

// ---------------------------------------------------------------------------
// compress: 1x1 conv 64->64 + BN + ReLU, thread-per-pixel, 64 fp32 acc.
// Output bf16 pixel-major [b][y][x][ci].
// ---------------------------------------------------------------------------
__global__ __launch_bounds__(256) void compress_kernel(
    const float* __restrict__ X, const float* __restrict__ Wc,
    const float* __restrict__ bias_c, ushort* __restrict__ out) {
  int p = blockIdx.x * 256 + threadIdx.x;
  int b = p >> 14, rem = p & 16383;
  const float* xb = X + ((size_t)b << 20) + rem;
  float acc[64];
#pragma unroll
  for (int co = 0; co < 64; ++co) acc[co] = 0.f;
#pragma unroll 4
  for (int ci = 0; ci < 64; ++ci) {
    float xv = xb[(size_t)ci << 14];
    const float* wr = Wc + (ci << 6);
#pragma unroll
    for (int co = 0; co < 64; ++co) acc[co] = fmaf(wr[co], xv, acc[co]);
  }
  alignas(16) ushort o[64];
#pragma unroll
  for (int co = 0; co < 64; ++co)
    o[co] = f2bf(fmaxf(acc[co] + bias_c[co], 0.f));
  uint4* dst = reinterpret_cast<uint4*>(out + (size_t)p * 64);
  const uint4* src = reinterpret_cast<const uint4*>(o);
#pragma unroll
  for (int u = 0; u < 8; ++u) dst[u] = src[u];
}

// ---------------------------------------------------------------------------
// encode: 3x3 conv (64->100) implicit GEMM on MFMA + fused bias + softmax(25)
// + pixel-shuffle de-interleave + bf16 pack.
// Output Wt: per pixel (b,y,x) 112 shorts: [r1(2) stride 56][k(25) as uint
// pairs (r2=0 low, r2=1 high)], 16B aligned.
// Epilogue: two 128-pixel phases reuse the Xt LDS buffer as fp32 wsm[128][100].
// GUARD: only e<100 m-tile slices are stored to wsm (mt=6 q>=1 and mt=7 are
// padding; storing them would clobber the next pixel's row / run off smem).
// ---------------------------------------------------------------------------
__global__ __launch_bounds__(256) void encode_mfma(
    const ushort* __restrict__ Wm1t, const ushort* __restrict__ Awt,
    const float* __restrict__ bias2, uint* __restrict__ Wtu) {
  __shared__ __align__(16) char smem[51200];
  ushort* Xt = (ushort*)smem;           // [324 pos][72 ci]
  const int tid = threadIdx.x;
  const int b = blockIdx.z;
  const int y0 = blockIdx.y * 16, x0 = blockIdx.x * 16;

  for (int u = tid; u < 2592; u += 256) {   // 324 pos x 8 ci-groups
    int pos = u >> 3, cg = u & 7;
    int iy = pos / 18, ix = pos - iy * 18;
    int gy = y0 + iy - 1, gx = x0 + ix - 1;
    uint4 v = make_uint4(0, 0, 0, 0);
    if ((unsigned)gy < 128u && (unsigned)gx < 128u)
      v = *reinterpret_cast<const uint4*>(
          Wm1t + ((((size_t)b << 14) + (gy << 7) + gx) << 6) + cg * 8);
    *reinterpret_cast<uint4*>(&Xt[pos * 72 + cg * 8]) = v;
  }
  __syncthreads();

  const int wave = tid >> 6, lane = tid & 63;
  const int q = lane >> 4, px = lane & 15;
  const int mtg = wave & 1, ntg = wave >> 1;

  float4v acc[4][8];
#pragma unroll
  for (int a = 0; a < 4; ++a)
#pragma unroll
    for (int i = 0; i < 8; ++i) acc[a][i] = (float4v){0.f, 0.f, 0.f, 0.f};

  const short8* Ap = reinterpret_cast<const short8*>(Awt);
#pragma unroll
  for (int kc = 0; kc < 18; ++kc) {
    const int t = kc >> 1, h = kc & 1;
    const int dy = t / 3, dx = t - dy * 3;
    short8 af[4];
#pragma unroll
    for (int a = 0; a < 4; ++a)
      af[a] = Ap[kc * 512 + (mtg * 4 + a) * 64 + lane];
    short8 bfr[8];
#pragma unroll
    for (int i = 0; i < 8; ++i) {
      int nt = ntg * 8 + i;
      bfr[i] = *reinterpret_cast<const short8*>(
          &Xt[((nt + dy) * 18 + (px + dx)) * 72 + h * 32 + q * 8]);
    }
#pragma unroll
    for (int a = 0; a < 4; ++a)
#pragma unroll
      for (int i = 0; i < 8; ++i)
        acc[a][i] = __builtin_amdgcn_mfma_f32_16x16x32_bf16(
            af[a], bfr[i], acc[a][i], 0, 0, 0);
  }
  __syncthreads();

  // ---- epilogue: bias + softmax + bf16 pack, two 128-pixel phases ----
  float* wsm = (float*)smem;            // [128 local px][100 e]
  const float4v* bias4 = (const float4v*)bias2;
  for (int half = 0; half < 2; ++half) {
    if (ntg == half) {
#pragma unroll
      for (int a = 0; a < 4; ++a) {
        int mt = mtg * 4 + a;
        int ebase = mt * 16 + q * 4;
        if (ebase < 100) {                 // skip padding e (would overflow row)
#pragma unroll
          for (int i = 0; i < 8; ++i) {
            int p = i * 16 + px;
            *reinterpret_cast<float4v*>(wsm + p * 100 + ebase) = acc[a][i];
          }
        }
      }
    }
    __syncthreads();
    if (tid < 128) {
      float4v v[25];
      const float* wp = wsm + tid * 100;
#pragma unroll
      for (int j = 0; j < 25; ++j)
        v[j] = *reinterpret_cast<const float4v*>(wp + 4 * j) + bias4[j];
      float4v m = v[0];
#pragma unroll
      for (int j = 1; j < 25; ++j) {
        m.x = fmaxf(m.x, v[j].x); m.y = fmaxf(m.y, v[j].y);
        m.z = fmaxf(m.z, v[j].z); m.w = fmaxf(m.w, v[j].w);
      }
      float4v s = (float4v){0.f, 0.f, 0.f, 0.f};
#pragma unroll
      for (int j = 0; j < 25; ++j) {
        v[j].x = __expf(v[j].x - m.x); v[j].y = __expf(v[j].y - m.y);
        v[j].z = __expf(v[j].z - m.z); v[j].w = __expf(v[j].w - m.w);
        s += v[j];
      }
      float i0 = 1.f / s.x, i1 = 1.f / s.y, i2 = 1.f / s.z, i3 = 1.f / s.w;
      int pix = b * 16384 + (y0 + half * 8 + (tid >> 4)) * 128 + x0 + (tid & 15);
      uint* w0p = Wtu + (size_t)pix * 56;
      uint* w1p = w0p + 28;
#pragma unroll
      for (int k = 0; k < 25; ++k) {
        w0p[k] = (uint)f2bf(v[k].x * i0) | ((uint)f2bf(v[k].y * i1) << 16);
        w1p[k] = (uint)f2bf(v[k].z * i2) | ((uint)f2bf(v[k].w * i3) << 16);
      }
    }
    __syncthreads();
  }
}

// ---------------------------------------------------------------------------
// carafe: apply only (softmax already done). 8x8 low-res tile per block.
// LDS = X tile only, pixel-major [144 pos][68 (64c + pad)] fp32 -> conflict-
// free b128 reads. Weights: 7 coalesced uint4 loads/thread from Wt.
// Thread (p, r1, cq): 32 channels x 2 r2 outputs, k-outer / c-inner float4.
// ---------------------------------------------------------------------------
__global__ __launch_bounds__(256) void carafe_kernel(
    const float* __restrict__ X, const uint* __restrict__ Wtu,
    float* __restrict__ out) {
  const int tid = threadIdx.x;
  const int b = blockIdx.z;
  const int y0 = blockIdx.y * 8, x0 = blockIdx.x * 8;
  __shared__ __align__(16) float xt[144 * 68];

  for (int idx = tid; idx < 9216; idx += 256) {
    int c = idx / 144;
    int rem = idx - c * 144;
    int iy = rem / 12, ix = rem - iy * 12;
    int gy = y0 + iy - 2, gx = x0 + ix - 2;
    float v = 0.f;
    if ((unsigned)gy < 128u && (unsigned)gx < 128u)
      v = X[(((size_t)(b * 64 + c)) << 14) + (gy << 7) + gx];
    xt[(iy * 12 + ix) * 68 + c] = v;
  }
  __syncthreads();

  const int p = tid & 63, q = tid >> 6;
  const int r1 = q & 1, cq = q >> 1;
  const int py = p >> 3, px = p & 7;

  int pix = b * 16384 + (y0 + py) * 128 + (x0 + px);
  const uint4* wq = reinterpret_cast<const uint4*>(Wtu + (size_t)pix * 56 + r1 * 28);
  alignas(16) uint w[28];
#pragma unroll
  for (int j = 0; j < 7; ++j) reinterpret_cast<uint4*>(w)[j] = wq[j];

  float2 acc[32];
#pragma unroll
  for (int i = 0; i < 32; ++i) acc[i] = make_float2(0.f, 0.f);

#pragma unroll
  for (int k = 0; k < 25; ++k) {
    const int dy = k / 5, dx = k - dy * 5;
    const float* bp = xt + ((py + dy) * 12 + (px + dx)) * 68 + cq * 32;
    float w0 = __uint_as_float(w[k] << 16);
    float w1 = __uint_as_float(w[k] & 0xffff0000u);
#pragma unroll
    for (int j = 0; j < 8; ++j) {
      float4v xv = *reinterpret_cast<const float4v*>(bp + 4 * j);
#pragma unroll
      for (int t = 0; t < 4; ++t) {
        acc[j * 4 + t].x = fmaf(w0, xv[t], acc[j * 4 + t].x);
        acc[j * 4 + t].y = fmaf(w1, xv[t], acc[j * 4 + t].y);
      }
    }
  }

  int yq = (y0 + py) * 2 + r1;
  int xq = (x0 + px) * 2;
#pragma unroll
  for (int ci = 0; ci < 32; ++ci) {
    int c = cq * 32 + ci;
    *reinterpret_cast<float2*>(
        out + ((size_t)(b * 64 + c) * 256 + yq) * 256 + xq) = acc[ci];
  }
}

// ---------------------------------------------------------------------------
extern "C" void kernel_launch(void* const* d_in, const int* in_sizes, int n_in,
                              void* d_out, int out_size, void* d_ws, size_t ws_size,
                              hipStream_t stream) {
  const float* X          = (const float*)d_in[0];
  const float* comp_w     = (const float*)d_in[1];
  const float* comp_gamma = (const float*)d_in[2];
  const float* comp_beta  = (const float*)d_in[3];
  const float* comp_mean  = (const float*)d_in[4];
  const float* comp_var   = (const float*)d_in[5];
  const float* enc_w      = (const float*)d_in[6];
  const float* enc_b      = (const float*)d_in[7];
  const float* enc_gamma  = (const float*)d_in[8];
  const float* enc_beta   = (const float*)d_in[9];
  const float* enc_mean   = (const float*)d_in[10];
  const float* enc_var    = (const float*)d_in[11];
  float* out = (float*)d_out;

  char* ws = (char*)d_ws;
  ushort* Wm1t  = (ushort*)(ws);                    //  8,388,608 B
  uint*   Wtu   = (uint*)(ws + 8388608);            // 14,680,064 B
  ushort* Awt   = (ushort*)(ws + 23068672);         //    147,456 B
  float*  Wc    = (float*)(ws + 23216128);          //     16,384 B
  float*  bias2 = (float*)(ws + 23232512);          //        512 B
  float*  biasc = (float*)(ws + 23233024);          //        256 B

  xform_kernel<<<52, 256, 0, stream>>>(enc_w, enc_gamma, enc_var,
                                       comp_w, comp_gamma, comp_var, Awt, Wc);
  bias_kernel<<<1, 256, 0, stream>>>(enc_b, enc_gamma, enc_beta, enc_mean,
                                     enc_var, comp_gamma, comp_beta, comp_mean,
                                     comp_var, bias2, biasc);
  compress_kernel<<<256, 256, 0, stream>>>(X, Wc, biasc, Wm1t);
  encode_mfma<<<dim3(8, 8, 4), 256, 0, stream>>>(Wm1t, Awt, bias2, Wtu);
  carafe_kernel<<<dim3(16, 16, 4), 256, 0, stream>>>(X, Wtu, out);
}